// Round 5
// baseline (905.637 us; speedup 1.0000x reference)
//
#include <hip/hip_runtime.h>
#include <hip/hip_fp16.h>

// Instant-NGP style hash-grid encoder, level-partitioned for L2 locality.
// N=1048576 points, 16 levels, LEVEL_DIM=2, HASHMAP_SIZE=2^19, BASE_RES=16.
//
// Hash identity: idx = ((cx*P0 + cy*P1 + cz*P2) & (2^19-1)) ^ lvl, in uint32
// (low 19 bits exact under 32-bit wraparound; corners >= 0; lvl < 16).
//
// R5 = R4 with the NT-store type fixed (clang ext_vector_type instead of
// HIP float4 class). Structure: R2 decode (balanced: every XCD gets exactly
// 2*nchunk blocks; time-partitioned: levels 0-7 fully dispatch before 8-15,
// so each XCD's 4 MiB L2 hosts exactly ONE 4 MiB table at a time) plus:
//   - f16 level-major intermediate ws[16][N] (__half2; |v|<=1e-4 so f16
//     adds <=3e-8 abs error vs 2e-6 threshold) -> halves ws traffic
//   - nontemporal x loads / ws stores+loads / out stores (streaming data
//     never evicts the L2-resident table; R3: FETCH 425->300 MB)
// Table gathers stay NORMAL loads: their 16x L2 reuse is the whole point.

#define NUM_LEVELS 16
#define HASHMAP_SIZE (1u << 19)
#define HASH_MASK (HASHMAP_SIZE - 1u)
#define BASE_RES 16
#define NXCD 8

typedef float f32x4 __attribute__((ext_vector_type(4)));

__global__ __launch_bounds__(256) void hash_level_kernel(
    const float* __restrict__ x,       // [N,3]
    const float* __restrict__ tables,  // [16, 2^19, 2]
    unsigned* __restrict__ ws,         // [16, N] of __half2
    int n, int nchunk) {
  // R2 decode: XCD k <- levels k and k+8 (HW round-robin wg->XCD on b%8),
  // level k+8's blocks dispatch strictly after all of level k's.
  const int b = blockIdx.x;
  const int lvl_lo = b % NXCD;
  const int r = b / NXCD;
  const int chunk = r % nchunk;
  const int lvl = lvl_lo + NXCD * (r / nchunk);

  const int i = chunk * 256 + (int)threadIdx.x;
  if (i >= n) return;

  const unsigned P0 = 1546061u, P1 = 1005013u, P2 = 1673733u;
  const float UB = (float)(1.0 - 1e-6);

  const float px = __builtin_nontemporal_load(x + 3 * (size_t)i + 0);
  const float py = __builtin_nontemporal_load(x + 3 * (size_t)i + 1);
  const float pz = __builtin_nontemporal_load(x + 3 * (size_t)i + 2);

  const float xn0 = fminf(fmaxf((px + 1.0f) * 0.5f, 0.0f), UB);
  const float xn1 = fminf(fmaxf((py + 1.0f) * 0.5f, 0.0f), UB);
  const float xn2 = fminf(fmaxf((pz + 1.0f) * 0.5f, 0.0f), UB);

  const float res = (float)(BASE_RES << lvl);
  const float s0 = xn0 * res, s1 = xn1 * res, s2 = xn2 * res;
  const float f0 = floorf(s0), f1 = floorf(s1), f2 = floorf(s2);
  const float fr0 = s0 - f0, fr1 = s1 - f1, fr2 = s2 - f2;
  const unsigned c0 = (unsigned)f0, c1 = (unsigned)f1, c2 = (unsigned)f2;

  const unsigned base = c0 * P0 + c1 * P1 + c2 * P2;  // uint32 wrap OK
  const float2* __restrict__ tbl =
      (const float2*)(tables + (size_t)lvl * HASHMAP_SIZE * 2);
  const float g0 = 1.0f - fr0, g1 = 1.0f - fr1, g2 = 1.0f - fr2;

  float acc0 = 0.0f, acc1 = 0.0f;
#pragma unroll
  for (int corner = 0; corner < 8; ++corner) {
    unsigned h = base;
    float w = 1.0f;
    if (corner & 4) { h += P0; w *= fr0; } else { w *= g0; }
    if (corner & 2) { h += P1; w *= fr1; } else { w *= g1; }
    if (corner & 1) { h += P2; w *= fr2; } else { w *= g2; }
    h = (h & HASH_MASK) ^ (unsigned)lvl;
    const float2 e = tbl[h];  // normal load: keep table hot in L2
    acc0 += e.x * w;
    acc1 += e.y * w;
  }

  // f16 pack (|acc| <= 1e-4 -> abs err <= 3e-8), coalesced streaming store
  const __half2 h2 = __floats2half2_rn(acc0, acc1);
  __builtin_nontemporal_store(*(const unsigned*)&h2, ws + (size_t)lvl * n + i);
}

__global__ __launch_bounds__(256) void transpose_kernel(
    const unsigned* __restrict__ ws,  // [16, N] of __half2
    float* __restrict__ out,          // [N, 32]
    int n) {
  const int i = blockIdx.x * blockDim.x + threadIdx.x;
  if (i >= n) return;

  float outv[2 * NUM_LEVELS];
#pragma unroll
  for (int lvl = 0; lvl < NUM_LEVELS; ++lvl) {
    const unsigned u = __builtin_nontemporal_load(ws + (size_t)lvl * n + i);
    const __half2 h2 = *(const __half2*)&u;
    const float2 f = __half22float2(h2);
    outv[2 * lvl + 0] = f.x;
    outv[2 * lvl + 1] = f.y;
  }
  f32x4* o = (f32x4*)(out + (size_t)i * (2 * NUM_LEVELS));
#pragma unroll
  for (int k = 0; k < 8; ++k) {
    __builtin_nontemporal_store(((const f32x4*)outv)[k], o + k);
  }
}

// fallback: direct f32 writes to out[N,32] (if ws too small; same R2 decode)
__global__ __launch_bounds__(256) void hash_direct_kernel(
    const float* __restrict__ x, const float* __restrict__ tables,
    float* __restrict__ out, int n, int nchunk) {
  const int b = blockIdx.x;
  const int lvl_lo = b % NXCD;
  const int r = b / NXCD;
  const int chunk = r % nchunk;
  const int lvl = lvl_lo + NXCD * (r / nchunk);
  const int i = chunk * 256 + (int)threadIdx.x;
  if (i >= n) return;

  const unsigned P0 = 1546061u, P1 = 1005013u, P2 = 1673733u;
  const float UB = (float)(1.0 - 1e-6);
  const float px = x[3 * (size_t)i + 0];
  const float py = x[3 * (size_t)i + 1];
  const float pz = x[3 * (size_t)i + 2];
  const float xn0 = fminf(fmaxf((px + 1.0f) * 0.5f, 0.0f), UB);
  const float xn1 = fminf(fmaxf((py + 1.0f) * 0.5f, 0.0f), UB);
  const float xn2 = fminf(fmaxf((pz + 1.0f) * 0.5f, 0.0f), UB);
  const float res = (float)(BASE_RES << lvl);
  const float s0 = xn0 * res, s1 = xn1 * res, s2 = xn2 * res;
  const float f0 = floorf(s0), f1 = floorf(s1), f2 = floorf(s2);
  const float fr0 = s0 - f0, fr1 = s1 - f1, fr2 = s2 - f2;
  const unsigned base =
      (unsigned)f0 * P0 + (unsigned)f1 * P1 + (unsigned)f2 * P2;
  const float2* __restrict__ tbl =
      (const float2*)(tables + (size_t)lvl * HASHMAP_SIZE * 2);
  const float g0 = 1.0f - fr0, g1 = 1.0f - fr1, g2 = 1.0f - fr2;
  float acc0 = 0.0f, acc1 = 0.0f;
#pragma unroll
  for (int corner = 0; corner < 8; ++corner) {
    unsigned h = base;
    float w = 1.0f;
    if (corner & 4) { h += P0; w *= fr0; } else { w *= g0; }
    if (corner & 2) { h += P1; w *= fr1; } else { w *= g1; }
    if (corner & 1) { h += P2; w *= fr2; } else { w *= g2; }
    h = (h & HASH_MASK) ^ (unsigned)lvl;
    const float2 e = tbl[h];
    acc0 += e.x * w;
    acc1 += e.y * w;
  }
  float2* o = (float2*)(out + (size_t)i * (2 * NUM_LEVELS) + 2 * lvl);
  *o = make_float2(acc0, acc1);
}

extern "C" void kernel_launch(void* const* d_in, const int* in_sizes, int n_in,
                              void* d_out, int out_size, void* d_ws, size_t ws_size,
                              hipStream_t stream) {
  const float* x = (const float*)d_in[0];
  const float* tables = (const float*)d_in[1];
  float* out = (float*)d_out;
  const int n = in_sizes[0] / 3;  // N points

  const int block = 256;
  const int nchunk = (n + block - 1) / block;
  const int nblocks = nchunk * NUM_LEVELS;

  const size_t ws_needed = (size_t)NUM_LEVELS * n * sizeof(unsigned);
  if (ws_size >= ws_needed) {
    unsigned* ws = (unsigned*)d_ws;
    hash_level_kernel<<<nblocks, block, 0, stream>>>(x, tables, ws, n, nchunk);
    transpose_kernel<<<nchunk, block, 0, stream>>>(ws, out, n);
  } else {
    hash_direct_kernel<<<nblocks, block, 0, stream>>>(x, tables, out, n, nchunk);
  }
}

// Round 6
// 660.492 us; speedup vs baseline: 1.3712x; 1.3712x over previous
//
#include <hip/hip_runtime.h>
#include <hip/hip_fp16.h>

// Instant-NGP style hash-grid encoder, level-partitioned for L2 locality.
// N=1048576 points, 16 levels, LEVEL_DIM=2, HASHMAP_SIZE=2^19, BASE_RES=16.
//
// Hash identity: idx = ((cx*P0 + cy*P1 + cz*P2) & (2^19-1)) ^ lvl, in uint32
// (low 19 bits exact under 32-bit wraparound; corners >= 0; lvl < 16).
//
// R6 structure (R2 decode + R3 wins + R5 fixes):
//  - balanced level->XCD: XCD k gets levels k and k+8, time-partitioned
//    (one 4 MiB table resident per XCD L2 at a time)
//  - f16 level-major intermediate ws[16][N] (__half2; |v|<=1e-4 -> f16 adds
//    <=3e-8 abs error vs 2e-6 threshold)
//  - NT loads for streaming x / ws; NT stores ONLY for ws (R5 lesson:
//    NT stores on the dense f32 output were ~10x slower -> plain stores)
//  - 2 points/thread in the main kernel: 16 outstanding gathers/thread
//    (tests latency-bound vs L2-service-bound; neutral if the latter)
// Table gathers stay NORMAL loads: their 16x L2 reuse is the whole point.

#define NUM_LEVELS 16
#define HASHMAP_SIZE (1u << 19)
#define HASH_MASK (HASHMAP_SIZE - 1u)
#define BASE_RES 16
#define NXCD 8
#define PPT 2  // points per thread (main kernel)

__global__ __launch_bounds__(256) void hash_level_kernel(
    const float* __restrict__ x,       // [N,3]
    const float* __restrict__ tables,  // [16, 2^19, 2]
    unsigned* __restrict__ ws,         // [16, N] of __half2
    int n, int nchunk) {
  // R2 decode: XCD k <- levels k and k+8 (HW round-robin wg->XCD on b%8),
  // level k+8's blocks dispatch strictly after all of level k's.
  const int b = blockIdx.x;
  const int lvl_lo = b % NXCD;
  const int r = b / NXCD;
  const int chunk = r % nchunk;
  const int lvl = lvl_lo + NXCD * (r / nchunk);

  const unsigned P0 = 1546061u, P1 = 1005013u, P2 = 1673733u;
  const float UB = (float)(1.0 - 1e-6);
  const float res = (float)(BASE_RES << lvl);
  const float2* __restrict__ tbl =
      (const float2*)(tables + (size_t)lvl * HASHMAP_SIZE * 2);

  const int ibase = chunk * (256 * PPT) + (int)threadIdx.x;

#pragma unroll
  for (int p = 0; p < PPT; ++p) {
    const int i = ibase + p * 256;
    if (i >= n) continue;

    const float px = __builtin_nontemporal_load(x + 3 * (size_t)i + 0);
    const float py = __builtin_nontemporal_load(x + 3 * (size_t)i + 1);
    const float pz = __builtin_nontemporal_load(x + 3 * (size_t)i + 2);

    const float xn0 = fminf(fmaxf((px + 1.0f) * 0.5f, 0.0f), UB);
    const float xn1 = fminf(fmaxf((py + 1.0f) * 0.5f, 0.0f), UB);
    const float xn2 = fminf(fmaxf((pz + 1.0f) * 0.5f, 0.0f), UB);

    const float s0 = xn0 * res, s1 = xn1 * res, s2 = xn2 * res;
    const float f0 = floorf(s0), f1 = floorf(s1), f2 = floorf(s2);
    const float fr0 = s0 - f0, fr1 = s1 - f1, fr2 = s2 - f2;
    const unsigned c0 = (unsigned)f0, c1 = (unsigned)f1, c2 = (unsigned)f2;

    const unsigned base = c0 * P0 + c1 * P1 + c2 * P2;  // uint32 wrap OK
    const float g0 = 1.0f - fr0, g1 = 1.0f - fr1, g2 = 1.0f - fr2;

    float acc0 = 0.0f, acc1 = 0.0f;
#pragma unroll
    for (int corner = 0; corner < 8; ++corner) {
      unsigned h = base;
      float w = 1.0f;
      if (corner & 4) { h += P0; w *= fr0; } else { w *= g0; }
      if (corner & 2) { h += P1; w *= fr1; } else { w *= g1; }
      if (corner & 1) { h += P2; w *= fr2; } else { w *= g2; }
      h = (h & HASH_MASK) ^ (unsigned)lvl;
      const float2 e = tbl[h];  // normal load: keep table hot in L2
      acc0 += e.x * w;
      acc1 += e.y * w;
    }

    // f16 pack (|acc| <= 1e-4 -> abs err <= 3e-8), coalesced streaming store
    const __half2 h2 = __floats2half2_rn(acc0, acc1);
    __builtin_nontemporal_store(*(const unsigned*)&h2,
                                ws + (size_t)lvl * n + i);
  }
}

__global__ __launch_bounds__(256) void transpose_kernel(
    const unsigned* __restrict__ ws,  // [16, N] of __half2
    float* __restrict__ out,          // [N, 32]
    int n) {
  const int i = blockIdx.x * blockDim.x + threadIdx.x;
  if (i >= n) return;

  float outv[2 * NUM_LEVELS];
#pragma unroll
  for (int lvl = 0; lvl < NUM_LEVELS; ++lvl) {
    const unsigned u = __builtin_nontemporal_load(ws + (size_t)lvl * n + i);
    const __half2 h2 = *(const __half2*)&u;
    const float2 f = __half22float2(h2);
    outv[2 * lvl + 0] = f.x;
    outv[2 * lvl + 1] = f.y;
  }
  // plain stores (R5 lesson: NT stores on dense output ~10x slower)
  float4* o = (float4*)(out + (size_t)i * (2 * NUM_LEVELS));
#pragma unroll
  for (int k = 0; k < 8; ++k) o[k] = ((const float4*)outv)[k];
}

// fallback: direct f32 writes to out[N,32] (if ws too small; same R2 decode)
__global__ __launch_bounds__(256) void hash_direct_kernel(
    const float* __restrict__ x, const float* __restrict__ tables,
    float* __restrict__ out, int n, int nchunk) {
  const int b = blockIdx.x;
  const int lvl_lo = b % NXCD;
  const int r = b / NXCD;
  const int chunk = r % nchunk;
  const int lvl = lvl_lo + NXCD * (r / nchunk);
  const int i = chunk * 256 + (int)threadIdx.x;
  if (i >= n) return;

  const unsigned P0 = 1546061u, P1 = 1005013u, P2 = 1673733u;
  const float UB = (float)(1.0 - 1e-6);
  const float px = x[3 * (size_t)i + 0];
  const float py = x[3 * (size_t)i + 1];
  const float pz = x[3 * (size_t)i + 2];
  const float xn0 = fminf(fmaxf((px + 1.0f) * 0.5f, 0.0f), UB);
  const float xn1 = fminf(fmaxf((py + 1.0f) * 0.5f, 0.0f), UB);
  const float xn2 = fminf(fmaxf((pz + 1.0f) * 0.5f, 0.0f), UB);
  const float res = (float)(BASE_RES << lvl);
  const float s0 = xn0 * res, s1 = xn1 * res, s2 = xn2 * res;
  const float f0 = floorf(s0), f1 = floorf(s1), f2 = floorf(s2);
  const float fr0 = s0 - f0, fr1 = s1 - f1, fr2 = s2 - f2;
  const unsigned base =
      (unsigned)f0 * P0 + (unsigned)f1 * P1 + (unsigned)f2 * P2;
  const float2* __restrict__ tbl =
      (const float2*)(tables + (size_t)lvl * HASHMAP_SIZE * 2);
  const float g0 = 1.0f - fr0, g1 = 1.0f - fr1, g2 = 1.0f - fr2;
  float acc0 = 0.0f, acc1 = 0.0f;
#pragma unroll
  for (int corner = 0; corner < 8; ++corner) {
    unsigned h = base;
    float w = 1.0f;
    if (corner & 4) { h += P0; w *= fr0; } else { w *= g0; }
    if (corner & 2) { h += P1; w *= fr1; } else { w *= g1; }
    if (corner & 1) { h += P2; w *= fr2; } else { w *= g2; }
    h = (h & HASH_MASK) ^ (unsigned)lvl;
    const float2 e = tbl[h];
    acc0 += e.x * w;
    acc1 += e.y * w;
  }
  float2* o = (float2*)(out + (size_t)i * (2 * NUM_LEVELS) + 2 * lvl);
  *o = make_float2(acc0, acc1);
}

extern "C" void kernel_launch(void* const* d_in, const int* in_sizes, int n_in,
                              void* d_out, int out_size, void* d_ws, size_t ws_size,
                              hipStream_t stream) {
  const float* x = (const float*)d_in[0];
  const float* tables = (const float*)d_in[1];
  float* out = (float*)d_out;
  const int n = in_sizes[0] / 3;  // N points

  const int block = 256;
  const size_t ws_needed = (size_t)NUM_LEVELS * n * sizeof(unsigned);
  if (ws_size >= ws_needed) {
    unsigned* ws = (unsigned*)d_ws;
    const int nchunk_main = (n + block * PPT - 1) / (block * PPT);
    hash_level_kernel<<<nchunk_main * NUM_LEVELS, block, 0, stream>>>(
        x, tables, ws, n, nchunk_main);
    const int nchunk_t = (n + block - 1) / block;
    transpose_kernel<<<nchunk_t, block, 0, stream>>>(ws, out, n);
  } else {
    const int nchunk = (n + block - 1) / block;
    hash_direct_kernel<<<nchunk * NUM_LEVELS, block, 0, stream>>>(
        x, tables, out, n, nchunk);
  }
}